// Round 14
// baseline (498.123 us; speedup 1.0000x reference)
//
#include <hip/hip_runtime.h>
#include <hip/hip_bf16.h>
#include <math.h>

// EGNN, N=6144, K=32, L=6, D=128, M=64, HE=256.
// Layer pipeline (2 dispatches/layer):
//   edge_kernel (STRIP=8 nodes/block): Q-rows needed by 8 consecutive nodes form
//     one contiguous 40-row band of PQ (neighbors are i+1..i+32 mod N) -> band
//     loaded ONCE to LDS (bf16); per node: hidden=silu(P+Q+rd*wr) -> MFMA
//     [32,256]@[256,64] -> m. No scattered gathers, no 64-bit addr math.
//   node_mlp: T=silu([feats|m]@nw1+nb1) -> feats=T@nw2+nb2+feats -> PQ_next.
// All matmuls bf16-MFMA (16x16x32), weights pre-packed to B-fragment order.
// Neighbor selection = {self} + 31 lowest-index adj entries (order-invariant sum).

#define NN    6144
#define KNN   32
#define NL    6
#define DD    128
#define MM    64
#define HEE   256
#define STRIP 8
#define BAND  (STRIP + KNN)   // 40 rows

typedef short bf16x8 __attribute__((ext_vector_type(8)));
typedef float f32x4  __attribute__((ext_vector_type(4)));

__device__ __forceinline__ float silu_f(float x) {
    return x / (1.0f + expf(-x));
}
__device__ __forceinline__ float silu_fast(float x) {
    return __fdividef(x, 1.0f + __expf(-x));
}
__device__ __forceinline__ unsigned short f2bf(float x) {
    __hip_bfloat16 b = __float2bfloat16(x);
    return *reinterpret_cast<unsigned short*>(&b);
}
__device__ __forceinline__ unsigned pack_bf2(float lo, float hi) {
    __hip_bfloat162 v = __float22bfloat162_rn(make_float2(lo, hi));
    return *reinterpret_cast<unsigned*>(&v);
}
__device__ __forceinline__ float bflo(unsigned u) {
    unsigned v = u << 16; return *reinterpret_cast<float*>(&v);
}
__device__ __forceinline__ float bfhi(unsigned u) {
    unsigned v = u & 0xffff0000u; return *reinterpret_cast<float*>(&v);
}

// ---------------- bf16 MFMA GEMM (encoder + layer-0 PQ only) ----------------
template<int KN, int AW, bool SILU, bool RESID, bool PQB>
__global__ __launch_bounds__(256)
void mfma_gemm(const float* __restrict__ A, const unsigned short* __restrict__ Bp,
               const float* __restrict__ bias, float* __restrict__ C, int Nn)
{
    constexpr int NKS = KN / 32;
    constexpr int LDA = KN + 8;
    constexpr int C4  = KN / 4;
    __shared__ unsigned short lsA[64 * LDA];
    const int t = threadIdx.x;
    const int row0 = blockIdx.y * 64, col0 = blockIdx.x * 64;

#pragma unroll
    for (int u0 = 0; u0 < 64 * C4; u0 += 256) {
        int u = u0 + t;
        int r = u / C4, c4 = u % C4;
        float4 v = make_float4(0.f, 0.f, 0.f, 0.f);
        if (c4 * 4 < AW) v = *(const float4*)&A[(size_t)(row0 + r) * AW + c4 * 4];
        *(uint2*)&lsA[r * LDA + c4 * 4] = make_uint2(pack_bf2(v.x, v.y), pack_bf2(v.z, v.w));
    }
    __syncthreads();

    const int w = t >> 6, l = t & 63;
    const int wr = w & 1, wc = w >> 1;
    const int lr = l & 15, lg = l >> 4;
    const int ct0 = blockIdx.x * 4 + wc * 2;
    const int aoff = (wr * 32 + lr) * LDA + lg * 8;
    f32x4 acc[2][2] = {};
#pragma unroll
    for (int ks = 0; ks < NKS; ++ks) {
        bf16x8 a0 = *(const bf16x8*)&lsA[aoff + ks * 32];
        bf16x8 a1 = *(const bf16x8*)&lsA[aoff + 16 * LDA + ks * 32];
        bf16x8 b0 = *(const bf16x8*)&Bp[((size_t)(ct0 * NKS + ks) * 64 + l) * 8];
        bf16x8 b1 = *(const bf16x8*)&Bp[((size_t)((ct0 + 1) * NKS + ks) * 64 + l) * 8];
        acc[0][0] = __builtin_amdgcn_mfma_f32_16x16x32_bf16(a0, b0, acc[0][0], 0, 0, 0);
        acc[0][1] = __builtin_amdgcn_mfma_f32_16x16x32_bf16(a0, b1, acc[0][1], 0, 0, 0);
        acc[1][0] = __builtin_amdgcn_mfma_f32_16x16x32_bf16(a1, b0, acc[1][0], 0, 0, 0);
        acc[1][1] = __builtin_amdgcn_mfma_f32_16x16x32_bf16(a1, b1, acc[1][1], 0, 0, 0);
    }
#pragma unroll
    for (int rt = 0; rt < 2; ++rt) {
#pragma unroll
        for (int ctl = 0; ctl < 2; ++ctl) {
            int col = col0 + wc * 32 + ctl * 16 + lr;
            float bv = (!PQB || col < 256) ? bias[col] : 0.0f;
#pragma unroll
            for (int r = 0; r < 4; ++r) {
                int row = row0 + wr * 32 + rt * 16 + lg * 4 + r;
                float v = acc[rt][ctl][r] + bv;
                if (SILU) v = silu_f(v);
                size_t off = (size_t)row * Nn + col;
                if (RESID) v += C[off];
                C[off] = v;
            }
        }
    }
}

// ---------------- fused node MLP, 16-row strips (384 blocks) ----------------
template<int KA, int KH, bool RESID, bool PQOUT>
__global__ __launch_bounds__(256, 4)
void node_mlp(const float* __restrict__ feats, const float* __restrict__ mbuf,
              const unsigned short* __restrict__ B1, const float* __restrict__ b1,
              const unsigned short* __restrict__ B2, const float* __restrict__ b2,
              const unsigned short* __restrict__ Bpq, const float* __restrict__ eb1,
              float* __restrict__ outF, float* __restrict__ PQ)
{
    constexpr int R   = 16;
    constexpr int LDA = KA + 8;
    constexpr int LDT = KH + 8;
    constexpr int KS1 = KA / 32;
    constexpr int KS2 = KH / 32;
    constexpr int CT1 = KH / 64;
    constexpr int C4A = KA / 4;
    __shared__ unsigned short lsA[R * LDA];
    __shared__ unsigned short lsT[R * LDT];
    __shared__ unsigned short lsF[PQOUT ? R * 136 : 4];
    const int t = threadIdx.x;
    const int r0 = blockIdx.x * R;

#pragma unroll
    for (int u0 = 0; u0 < R * C4A; u0 += 256) {
        int u = u0 + t;
        int r = u / C4A, c = (u % C4A) * 4;
        float4 v;
        if (KA == 128 || c < 128) v = *(const float4*)&feats[(size_t)(r0 + r) * DD + c];
        else                      v = *(const float4*)&mbuf[(size_t)(r0 + r) * MM + (c - 128)];
        *(uint2*)&lsA[r * LDA + c] = make_uint2(pack_bf2(v.x, v.y), pack_bf2(v.z, v.w));
    }
    __syncthreads();

    const int w = t >> 6, l = t & 63;
    const int lr = l & 15, lg = l >> 4;

    // ---- n1: T = silu(A@B1 + b1) ----
    {
        f32x4 acc[CT1] = {};
#pragma unroll
        for (int ks = 0; ks < KS1; ++ks) {
            bf16x8 a0 = *(const bf16x8*)&lsA[lr * LDA + ks * 32 + lg * 8];
#pragma unroll
            for (int ct = 0; ct < CT1; ++ct) {
                bf16x8 b = *(const bf16x8*)&B1[((size_t)((w * CT1 + ct) * KS1 + ks) * 64 + l) * 8];
                acc[ct] = __builtin_amdgcn_mfma_f32_16x16x32_bf16(a0, b, acc[ct], 0, 0, 0);
            }
        }
#pragma unroll
        for (int ct = 0; ct < CT1; ++ct) {
            int col = (w * CT1 + ct) * 16 + lr;
            float bv = b1[col];
#pragma unroll
            for (int r = 0; r < 4; ++r)
                lsT[(lg * 4 + r) * LDT + col] = f2bf(silu_f(acc[ct][r] + bv));
        }
    }
    __syncthreads();

    // ---- n2: out = T@B2 + b2 (+resid) ----
    {
        f32x4 acc[2] = {};
#pragma unroll
        for (int ks = 0; ks < KS2; ++ks) {
            bf16x8 a0 = *(const bf16x8*)&lsT[lr * LDT + ks * 32 + lg * 8];
#pragma unroll
            for (int ct = 0; ct < 2; ++ct) {
                bf16x8 b = *(const bf16x8*)&B2[((size_t)((w * 2 + ct) * KS2 + ks) * 64 + l) * 8];
                acc[ct] = __builtin_amdgcn_mfma_f32_16x16x32_bf16(a0, b, acc[ct], 0, 0, 0);
            }
        }
#pragma unroll
        for (int ct = 0; ct < 2; ++ct) {
            int col = (w * 2 + ct) * 16 + lr;
            float bv = b2[col];
#pragma unroll
            for (int r = 0; r < 4; ++r) {
                int row = lg * 4 + r;
                size_t off = (size_t)(r0 + row) * DD + col;
                float v = acc[ct][r] + bv;
                if (RESID) v += feats[off];
                outF[off] = v;
                if (PQOUT) lsF[row * 136 + col] = f2bf(v);
            }
        }
    }

    // ---- PQ for next layer ----
    if (PQOUT) {
        __syncthreads();
        f32x4 acc[8] = {};
#pragma unroll
        for (int ks = 0; ks < 4; ++ks) {
            bf16x8 a0 = *(const bf16x8*)&lsF[lr * 136 + ks * 32 + lg * 8];
#pragma unroll
            for (int ct = 0; ct < 8; ++ct) {
                int ctg = w * 8 + ct;
                bf16x8 b = *(const bf16x8*)&Bpq[((size_t)(ctg * 4 + ks) * 64 + l) * 8];
                acc[ct] = __builtin_amdgcn_mfma_f32_16x16x32_bf16(a0, b, acc[ct], 0, 0, 0);
            }
        }
#pragma unroll
        for (int ct = 0; ct < 8; ++ct) {
            int col = (w * 8 + ct) * 16 + lr;
            float bv = (col < 256) ? eb1[col] : 0.0f;
#pragma unroll
            for (int r = 0; r < 4; ++r)
                PQ[(size_t)(r0 + lg * 4 + r) * 512 + col] = acc[ct][r] + bv;
        }
    }
}

// ---------------- unified weight pre-pack (unchanged layouts) ---------------
__global__ __launch_bounds__(256)
void pack_all(const float* __restrict__ ew1, const float* __restrict__ ew2,
              const float* __restrict__ nw1, const float* __restrict__ nw2,
              const float* __restrict__ dw1, const float* __restrict__ dw2,
              const float* __restrict__ wenc,
              unsigned short* __restrict__ Bpq, unsigned short* __restrict__ Bn1,
              unsigned short* __restrict__ Bn2, unsigned short* __restrict__ w2p,
              unsigned short* __restrict__ Bd1, unsigned short* __restrict__ Bd2,
              unsigned short* __restrict__ Benc)
{
    const int t = threadIdx.x;
    const int u = blockIdx.x * 4 + (t >> 6);
    if (u >= 2008) return;
    const int lane = t & 63;
    const float* src; unsigned short* dst;
    int nks, nc, ctd, ctc, ks, kmax = 1 << 30;
    if (u < 1920) {
        int l = u / 320, r = u % 320;
        if (r < 128) {                    // PQ: ew1 split-source, 32 ct x 4 ks
            ctd = r >> 2; ks = r & 3; nks = 4; nc = 256; ctc = ctd & 15;
            src = ew1 + (size_t)l * 257 * 256 + (ctd >= 16 ? 128 * 256 : 0);
            dst = Bpq + (size_t)l * 65536;
        } else if (r < 224) {             // n1: [192][256], 16 ct x 6 ks
            int rr = r - 128; ctd = rr / 6; ks = rr % 6; nks = 6; nc = 256; ctc = ctd;
            src = nw1 + (size_t)l * 192 * 256; dst = Bn1 + (size_t)l * 49152;
        } else if (r < 288) {             // n2: [256][128], 8 ct x 8 ks
            int rr = r - 224; ctd = rr >> 3; ks = rr & 7; nks = 8; nc = 128; ctc = ctd;
            src = nw2 + (size_t)l * 256 * 128; dst = Bn2 + (size_t)l * 32768;
        } else {                          // ew2: [256][64], 4 ct x 8 ks
            int rr = r - 288; ctd = rr >> 3; ks = rr & 7; nks = 8; nc = 64; ctc = ctd;
            src = ew2 + (size_t)l * 256 * 64; dst = w2p + (size_t)l * 16384;
        }
    } else if (u < 1984) {                // dw1/dw2: [128][128], 8 ct x 4 ks
        int rr = u - 1920;
        int m = rr >> 5; rr &= 31;
        ctd = rr >> 2; ks = rr & 3; nks = 4; nc = 128; ctc = ctd;
        src = m ? dw2 : dw1; dst = m ? Bd2 : Bd1;
    } else {                              // encoder: [68][128] pad K->96, 8 ct x 3 ks
        int rr = u - 1984;
        ctd = rr / 3; ks = rr % 3; nks = 3; nc = 128; ctc = ctd; kmax = 68;
        src = wenc; dst = Benc;
    }
    const int k0 = ks * 32 + (lane >> 4) * 8;
    const int col = ctc * 16 + (lane & 15);
    unsigned short* o = dst + ((size_t)(ctd * nks + ks) * 64 + lane) * 8;
#pragma unroll
    for (int j = 0; j < 8; ++j)
        o[j] = (k0 + j < kmax) ? f2bf(src[(size_t)(k0 + j) * nc + col]) : (unsigned short)0;
}

// ---------------- neighbor structure: thread = (node, k) edge slot ----------
__global__ __launch_bounds__(256)
void neighbor_kernel(const int* __restrict__ ei, const float* __restrict__ coords,
                     int* __restrict__ idx, float* __restrict__ rd)
{
    const int gid = blockIdx.x * 256 + threadIdx.x;
    const int i = gid >> 5, k = gid & 31;
    const int j = ei[(size_t)NN * KNN + (size_t)i * KNN + k];
    int dmax = j, kmax = k;
#pragma unroll
    for (int m = 1; m < 32; m <<= 1) {
        int od = __shfl_xor(dmax, m);
        int ok = __shfl_xor(kmax, m);
        if (od > dmax) { dmax = od; kmax = ok; }
    }
    int pos, jw;
    if (k == kmax) { pos = 0; jw = i; }
    else { pos = (k < kmax) ? k + 1 : k; jw = j; }
    float dx = coords[3 * i]     - coords[3 * jw];
    float dy = coords[3 * i + 1] - coords[3 * jw + 1];
    float dz = coords[3 * i + 2] - coords[3 * jw + 2];
    rd[(size_t)i * KNN + pos]  = dx * dx + dy * dy + dz * dz;
    idx[(size_t)i * KNN + pos] = jw;
}

// ---------------- strip edge kernel: 8 nodes/block, banded Q in LDS ---------
// Band property: all neighbors of nodes [i0,i0+8) lie in rows (i0..i0+39) mod N.
// Offsets computed generically as (idx - i0) mod N from the idx buffer.
__global__ __launch_bounds__(256, 3)
void edge_kernel(const float* __restrict__ PQ, const float* __restrict__ wr,
                 const unsigned short* __restrict__ w2p, const float* __restrict__ eb2,
                 const int* __restrict__ idx, const float* __restrict__ rd,
                 float* __restrict__ mbuf)
{
    __shared__ unsigned short lsQ[BAND * 264];    // Q band bf16
    __shared__ unsigned short lsP[STRIP * 264];   // P rows bf16
    __shared__ unsigned short lsH[32 * 264];      // hidden bf16 (per node, reused)
    __shared__ float lsWr[HEE];
    __shared__ float lsRd[STRIP][KNN];
    __shared__ int   lsOff[STRIP][KNN];
    __shared__ float lsPart[2][4][16];
    __shared__ float lsM[STRIP][MM];

    const int t = threadIdx.x;
    const int i0 = blockIdx.x * STRIP;

    // Q band: 40 rows x 256 cols fp32 -> bf16 (coalesced)
#pragma unroll
    for (int it = 0; it < 10; ++it) {
        int u = it * 256 + t;
        int r = u >> 6, c4 = (u & 63) * 4;
        int row = i0 + r; if (row >= NN) row -= NN;
        float4 v = *(const float4*)&PQ[(size_t)row * 512 + 256 + c4];
        *(uint2*)&lsQ[r * 264 + c4] = make_uint2(pack_bf2(v.x, v.y), pack_bf2(v.z, v.w));
    }
    // P rows: 8 x 256
#pragma unroll
    for (int it = 0; it < 2; ++it) {
        int u = it * 256 + t;
        int r = u >> 6, c4 = (u & 63) * 4;
        float4 v = *(const float4*)&PQ[(size_t)(i0 + r) * 512 + c4];
        *(uint2*)&lsP[r * 264 + c4] = make_uint2(pack_bf2(v.x, v.y), pack_bf2(v.z, v.w));
    }
    lsWr[t] = wr[t];
    {
        int n = t >> 5, k = t & 31;      // 8*32 = 256 entries, one per thread
        int j = idx[(size_t)(i0 + n) * KNN + k];
        int off = j - i0; if (off < 0) off += NN;
        lsOff[n][k] = off;               // in [0, 40)
        lsRd[n][k]  = rd[(size_t)(i0 + n) * KNN + k];
    }
    __syncthreads();

    const int w = t >> 6, l = t & 63;
    const int rt = w & 1, cb = (w >> 1) * 2;
    const int lr = l & 15, lg = l >> 4;
    const int c0 = (t & 63) * 4;
    const int rg = t >> 6;
    const float e0 = eb2[cb * 16 + lr], e1 = eb2[(cb + 1) * 16 + lr];
    const float4 w4 = *(const float4*)&lsWr[c0];
    const int arow = rt * 16 + lr;

    for (int n = 0; n < STRIP; ++n) {
        // Phase A: hidden rows rg*8..rg*8+7, cols c0..c0+3 (all LDS-resident)
        {
            uint2 pu = *(const uint2*)&lsP[n * 264 + c0];
            float p0 = bflo(pu.x), p1 = bfhi(pu.x);
            float p2 = bflo(pu.y), p3 = bfhi(pu.y);
#pragma unroll
            for (int k = 0; k < 8; ++k) {
                int kk = rg * 8 + k;
                int off = lsOff[n][kk];
                float rdk = lsRd[n][kk];
                uint2 qu = *(const uint2*)&lsQ[off * 264 + c0];
                float a0 = silu_fast(fmaf(rdk, w4.x, p0) + bflo(qu.x));
                float a1 = silu_fast(fmaf(rdk, w4.y, p1) + bfhi(qu.x));
                float a2 = silu_fast(fmaf(rdk, w4.z, p2) + bflo(qu.y));
                float a3 = silu_fast(fmaf(rdk, w4.w, p3) + bfhi(qu.y));
                *(uint2*)&lsH[kk * 264 + c0] =
                    make_uint2(pack_bf2(a0, a1), pack_bf2(a2, a3));
            }
        }
        __syncthreads();                 // lsH ready (and prev lsPart consumed)

        // Phase B: [32,256]@[256,64] MFMA, silu, k-reduce
        f32x4 acc0 = {0.f, 0.f, 0.f, 0.f}, acc1 = {0.f, 0.f, 0.f, 0.f};
#pragma unroll
        for (int ks = 0; ks < 8; ++ks) {
            bf16x8 a  = *(const bf16x8*)&lsH[arow * 264 + ks * 32 + lg * 8];
            bf16x8 b0 = *(const bf16x8*)&w2p[(size_t)(cb * 8 + ks) * 512 + l * 8];
            bf16x8 b1 = *(const bf16x8*)&w2p[(size_t)((cb + 1) * 8 + ks) * 512 + l * 8];
            acc0 = __builtin_amdgcn_mfma_f32_16x16x32_bf16(a, b0, acc0, 0, 0, 0);
            acc1 = __builtin_amdgcn_mfma_f32_16x16x32_bf16(a, b1, acc1, 0, 0, 0);
        }
        float s0 = 0.f, s1 = 0.f;
#pragma unroll
        for (int r = 0; r < 4; ++r) {
            s0 += silu_fast(acc0[r] + e0);
            s1 += silu_fast(acc1[r] + e1);
        }
        s0 += __shfl_xor(s0, 16); s0 += __shfl_xor(s0, 32);
        s1 += __shfl_xor(s1, 16); s1 += __shfl_xor(s1, 32);
        if (lg == 0) { lsPart[rt][cb][lr] = s0; lsPart[rt][cb + 1][lr] = s1; }
        __syncthreads();                 // lsPart ready; lsH reads done
        if (t < MM)
            lsM[n][t] = lsPart[0][t >> 4][t & 15] + lsPart[1][t >> 4][t & 15];
    }
    __syncthreads();
#pragma unroll
    for (int it = 0; it < 2; ++it) {
        int u = it * 256 + t;            // 8*64 = 512 m values, coalesced
        mbuf[(size_t)(i0 + (u >> 6)) * MM + (u & 63)] = lsM[u >> 6][u & 63];
    }
}

// ---------------- deterministic column sum (stage 1) ------------------------
__global__ __launch_bounds__(256)
void colsum_kernel(const float* __restrict__ F, float* __restrict__ partial)
{
    __shared__ float ls[2][DD];
    const int b = blockIdx.x;
    const int t = threadIdx.x;
    const int c = t & 127, rg = t >> 7;
    float s = 0.0f;
    const int r0 = b * 64;
    for (int r = rg; r < 64; r += 2) s += F[(size_t)(r0 + r) * DD + c];
    ls[rg][c] = s;
    __syncthreads();
    if (t < DD) partial[(size_t)b * DD + t] = ls[0][t] + ls[1][t];
}

// ---------------- graph decoder + normalize (single block) ------------------
__global__ __launch_bounds__(128)
void final_kernel(const float* __restrict__ partial, const float* __restrict__ gw1,
                  const float* __restrict__ gb1, const float* __restrict__ gw2,
                  const float* __restrict__ gb2, float* __restrict__ out)
{
    __shared__ float lg[DD], lu[DD], red[DD];
    const int t = threadIdx.x;
    float s = 0.0f;
    for (int b = 0; b < 96; ++b) s += partial[(size_t)b * DD + t];
    lg[t] = s;
    __syncthreads();
    float a = 0.0f;
    for (int c = 0; c < DD; ++c) a += lg[c] * gw1[(size_t)c * DD + t];
    lu[t] = silu_f(a + gb1[t]);
    __syncthreads();
    float v = 0.0f;
    for (int c = 0; c < DD; ++c) v += lu[c] * gw2[(size_t)c * DD + t];
    v += gb2[t];
    red[t] = v * v;
    __syncthreads();
    for (int sft = 64; sft > 0; sft >>= 1) {
        if (t < sft) red[t] += red[t + sft];
        __syncthreads();
    }
    float nrm = sqrtf(red[0]);
    out[t] = v / fmaxf(nrm, 1e-12f);
}

// ---------------------------------------------------------------------------
extern "C" void kernel_launch(void* const* d_in, const int* in_sizes, int n_in,
                              void* d_out, int out_size, void* d_ws, size_t ws_size,
                              hipStream_t stream)
{
    const float* x      = (const float*)d_in[0];
    const float* coords = (const float*)d_in[1];
    const int*   ei     = (const int*)d_in[2];
    const float* w_enc  = (const float*)d_in[3];
    const float* b_enc  = (const float*)d_in[4];
    const float* ew1    = (const float*)d_in[5];
    const float* eb1    = (const float*)d_in[6];
    const float* ew2    = (const float*)d_in[7];
    const float* eb2    = (const float*)d_in[8];
    const float* nw1    = (const float*)d_in[9];
    const float* nb1    = (const float*)d_in[10];
    const float* nw2    = (const float*)d_in[11];
    const float* nb2    = (const float*)d_in[12];
    const float* dw1    = (const float*)d_in[13];
    const float* db1    = (const float*)d_in[14];
    const float* dw2    = (const float*)d_in[15];
    const float* db2    = (const float*)d_in[16];
    const float* gw1    = (const float*)d_in[17];
    const float* gb1    = (const float*)d_in[18];
    const float* gw2    = (const float*)d_in[19];
    const float* gb2    = (const float*)d_in[20];
    float* out = (float*)d_out;

    // workspace layout (float units)
    float* ws      = (float*)d_ws;
    float* feats   = ws;                          // 6144*128
    float* PQ      = feats + 786432;              // 6144*512 (decoder reuses as Fbuf)
    float* mbuf    = PQ + 3145728;                // 6144*64
    int*   idxbuf  = (int*)(mbuf + 393216);       // 6144*32
    float* rdbuf   = (float*)(idxbuf + 196608);   // 6144*32
    float* partial = rdbuf + 196608;              // 96*128
    unsigned short* w2p  = (unsigned short*)(partial + 12288);  // 6*16384
    unsigned short* Bpq  = w2p + 98304;           // 6*65536
    unsigned short* Bn1  = Bpq + 393216;          // 6*49152
    unsigned short* Bn2  = Bn1 + 294912;          // 6*32768
    unsigned short* Bd1  = Bn2 + 196608;          // 16384
    unsigned short* Bd2  = Bd1 + 16384;           // 16384
    unsigned short* Benc = Bd2 + 16384;           // 24*64*8 = 12288

    float* Fbuf = PQ;                  // decoder output (PQ dead by then)

    dim3 blk(256);

    neighbor_kernel<<<768, blk, 0, stream>>>(ei, coords, idxbuf, rdbuf);
    pack_all<<<502, blk, 0, stream>>>(ew1, ew2, nw1, nw2, dw1, dw2, w_enc,
                                      Bpq, Bn1, Bn2, w2p, Bd1, Bd2, Benc);
    // encoder (MFMA, K=68 padded to 96) -> feats
    mfma_gemm<96, 68, false, false, false><<<dim3(2, 96), blk, 0, stream>>>(
        x, Benc, b_enc, feats, 128);
    // layer-0 PQ (subsequent PQs fused into node_mlp)
    mfma_gemm<128, 128, false, false, true><<<dim3(8, 96), blk, 0, stream>>>(
        feats, Bpq, eb1, PQ, 512);

    for (int l = 0; l < NL; ++l) {
        edge_kernel<<<NN / STRIP, blk, 0, stream>>>(
            PQ, ew1 + (size_t)l * 257 * 256 + 256 * 256,
            w2p + (size_t)l * 16384, eb2 + l * 64, idxbuf, rdbuf, mbuf);
        if (l < NL - 1) {
            node_mlp<192, 256, true, true><<<384, blk, 0, stream>>>(
                feats, mbuf, Bn1 + (size_t)l * 49152, nb1 + l * 256,
                Bn2 + (size_t)l * 32768, nb2 + l * 128,
                Bpq + (size_t)(l + 1) * 65536, eb1 + (l + 1) * 256, feats, PQ);
        } else {
            node_mlp<192, 256, true, false><<<384, blk, 0, stream>>>(
                feats, mbuf, Bn1 + (size_t)l * 49152, nb1 + l * 256,
                Bn2 + (size_t)l * 32768, nb2 + l * 128,
                nullptr, nullptr, feats, nullptr);
        }
    }

    // node decoder (dw1+dw2 fused, no resid) -> Fbuf
    node_mlp<128, 128, false, false><<<384, blk, 0, stream>>>(
        feats, nullptr, Bd1, db1, Bd2, db2, nullptr, nullptr, Fbuf, nullptr);
    // graph sum + graph decoder + normalize
    colsum_kernel<<<96, blk, 0, stream>>>(Fbuf, partial);
    final_kernel<<<1, dim3(128), 0, stream>>>(partial, gw1, gb1, gw2, gb2, out);
}